// Round 1
// baseline (81.418 us; speedup 1.0000x reference)
//
#include <hip/hip_runtime.h>

#define HID 1024
#define BATCH 256
#define KTASK 4096
#define TPB 8            // tasks per block
#define NCOL (TPB * 8)   // 64 output columns per block
#define KC 32            // k-chunk per step
#define NSTEPS (HID / KC)
#define STRIDE 80        // LDS row stride in bytes (64B data + 16B pad -> 2-way max)

typedef __bf16 bf16x8 __attribute__((ext_vector_type(8)));
typedef float f32x4 __attribute__((ext_vector_type(4)));

static __device__ __forceinline__ bf16x8 cvt8(const float4& a, const float4& b) {
    bf16x8 r;
    r[0] = (__bf16)a.x; r[1] = (__bf16)a.y; r[2] = (__bf16)a.z; r[3] = (__bf16)a.w;
    r[4] = (__bf16)b.x; r[5] = (__bf16)b.y; r[6] = (__bf16)b.z; r[7] = (__bf16)b.w;
    return r;
}

__global__ __launch_bounds__(256, 2)
void mtc_kernel(const float* __restrict__ emb, const float* __restrict__ W1,
                const float* __restrict__ b1, const float* __restrict__ W2,
                const float* __restrict__ b2, const int* __restrict__ tids,
                float* __restrict__ out)
{
    __shared__ __align__(16) char wbuf[2][NCOL * STRIDE];

    const int t = threadIdx.x;
    const int lane = t & 63;
    const int w = t >> 6;
    const int blk = blockIdx.x;

    // ---- staging assignment: LDS row srow (one (task,o) pair), quarter sq (8 floats)
    const int srow = t >> 2;            // 0..63
    const int sq   = t & 3;             // 0..3
    const int stask = tids[blk * TPB + (srow >> 3)];
    const float* sgp = W1 + (size_t)stask * (8 * HID) + (size_t)(srow & 7) * HID + sq * 8;
    char* const sld0 = &wbuf[0][0] + srow * STRIDE + sq * 16;
    char* const sld1 = &wbuf[1][0] + srow * STRIDE + sq * 16;

    // ---- A fragment source: wave w, b-tile bt -> row w*64 + bt*16 + (lane&15)
    const float* agp = emb + (size_t)(w * 64 + (lane & 15)) * HID + (lane >> 4) * 8;

    // ---- B fragment LDS offset: row nt*16 + (lane&15), k-group (lane>>4)*8
    const int boff = (lane & 15) * STRIDE + (lane >> 4) * 16;

    f32x4 acc[4][4];
    const f32x4 zero = {0.f, 0.f, 0.f, 0.f};
#pragma unroll
    for (int i = 0; i < 4; ++i)
#pragma unroll
        for (int j = 0; j < 4; ++j) acc[i][j] = zero;

    // ---- prologue: stage k-step 0, load A fragments for step 0
    float4 s0 = *(const float4*)(sgp);
    float4 s1 = *(const float4*)(sgp + 4);
    float4 a0[4], a1[4];
#pragma unroll
    for (int bt = 0; bt < 4; ++bt) {
        const float* ap = agp + (size_t)bt * (16 * HID);
        a0[bt] = *(const float4*)(ap);
        a1[bt] = *(const float4*)(ap + 4);
    }
    *(bf16x8*)sld0 = cvt8(s0, s1);
    bf16x8 afr[4];
#pragma unroll
    for (int bt = 0; bt < 4; ++bt) afr[bt] = cvt8(a0[bt], a1[bt]);
    __syncthreads();

    for (int s = 0; s < NSTEPS; ++s) {
        const int cur = s & 1;
        const bool more = (s + 1) < NSTEPS;
        float4 ns0, ns1, na0[4], na1[4];
        if (more) {
            const float* sp = sgp + (s + 1) * KC;
            ns0 = *(const float4*)(sp);
            ns1 = *(const float4*)(sp + 4);
#pragma unroll
            for (int bt = 0; bt < 4; ++bt) {
                const float* ap = agp + (s + 1) * KC + (size_t)bt * (16 * HID);
                na0[bt] = *(const float4*)(ap);
                na1[bt] = *(const float4*)(ap + 4);
            }
        }
        const char* rb = &wbuf[cur][0];
#pragma unroll
        for (int nt = 0; nt < 4; ++nt) {
            bf16x8 bf = *(const bf16x8*)(rb + nt * (16 * STRIDE) + boff);
#pragma unroll
            for (int bt = 0; bt < 4; ++bt)
                acc[bt][nt] = __builtin_amdgcn_mfma_f32_16x16x32_bf16(afr[bt], bf, acc[bt][nt], 0, 0, 0);
        }
        if (more) {
            *(bf16x8*)(cur ? sld0 : sld1) = cvt8(ns0, ns1);
#pragma unroll
            for (int bt = 0; bt < 4; ++bt) afr[bt] = cvt8(na0[bt], na1[bt]);
        }
        __syncthreads();
    }

    // ---- epilogue: +b1, relu, *w2, reduce over o (8 lanes), +b2, store task-major
    const int col = lane & 15;
    const int rgrp = lane >> 4;     // C row = rgrp*4 + r
    const int o = col & 7;
#pragma unroll
    for (int nt = 0; nt < 4; ++nt) {
        const int tl = nt * 2 + (col >> 3);       // task-local 0..7
        const int task = tids[blk * TPB + tl];
        const float bb1 = b1[task * 8 + o];
        const float ww2 = W2[task * 8 + o];
#pragma unroll
        for (int bt = 0; bt < 4; ++bt) {
            float v[4];
#pragma unroll
            for (int r = 0; r < 4; ++r) {
                float x = acc[bt][nt][r] + bb1;
                x = x > 0.f ? x : 0.f;
                v[r] = x * ww2;
            }
#pragma unroll
            for (int m = 1; m <= 4; m <<= 1) {
#pragma unroll
                for (int r = 0; r < 4; ++r) v[r] += __shfl_xor(v[r], m, 64);
            }
            if ((lane & 7) == 0) {
                const float bb2 = b2[task];
                const int brow = w * 64 + bt * 16 + rgrp * 4;
                float4 o4 = make_float4(v[0] + bb2, v[1] + bb2, v[2] + bb2, v[3] + bb2);
                *(float4*)(out + (size_t)(blk * TPB + tl) * BATCH + brow) = o4;
            }
        }
    }
}

extern "C" void kernel_launch(void* const* d_in, const int* in_sizes, int n_in,
                              void* d_out, int out_size, void* d_ws, size_t ws_size,
                              hipStream_t stream) {
    const float* emb = (const float*)d_in[0];
    const float* W1  = (const float*)d_in[1];
    const float* b1  = (const float*)d_in[2];
    const float* W2  = (const float*)d_in[3];
    const float* b2  = (const float*)d_in[4];
    const int*   tid = (const int*)d_in[5];
    float* outp = (float*)d_out;

    dim3 grid(KTASK / TPB);   // 512 blocks
    dim3 block(256);
    mtc_kernel<<<grid, block, 0, stream>>>(emb, W1, b1, W2, b2, tid, outp);
}

// Round 2
// 54.040 us; speedup vs baseline: 1.5066x; 1.5066x over previous
//
#include <hip/hip_runtime.h>

#define HID 1024
#define BATCH 256
#define KTASK 4096
#define TPB 8             // tasks per block
#define NCOL 64           // 8 tasks * 8 hidden-outputs
#define KC 32             // k per step
#define NSTEPS (HID / KC) // 32
#define STRIDE 80         // LDS row stride bytes (64 data + 16 pad)

typedef __bf16 bf16x8 __attribute__((ext_vector_type(8)));
typedef __bf16 bf16x4 __attribute__((ext_vector_type(4)));
typedef float f32x4 __attribute__((ext_vector_type(4)));

static __device__ __forceinline__ bf16x8 cvt8(const float4& a, const float4& b) {
    bf16x8 r;
    r[0] = (__bf16)a.x; r[1] = (__bf16)a.y; r[2] = (__bf16)a.z; r[3] = (__bf16)a.w;
    r[4] = (__bf16)b.x; r[5] = (__bf16)b.y; r[6] = (__bf16)b.z; r[7] = (__bf16)b.w;
    return r;
}

__global__ __launch_bounds__(256, 4)
void cvt_emb_kernel(const float* __restrict__ emb, __bf16* __restrict__ dst) {
    int i = (blockIdx.x * 256 + threadIdx.x) * 4;
    float4 v = *(const float4*)(emb + i);
    bf16x4 r;
    r[0] = (__bf16)v.x; r[1] = (__bf16)v.y; r[2] = (__bf16)v.z; r[3] = (__bf16)v.w;
    *(bf16x4*)(dst + i) = r;
}

__global__ __launch_bounds__(256, 4)
void mtc_kernel(const __bf16* __restrict__ embb, const float* __restrict__ W1,
                const float* __restrict__ b1, const float* __restrict__ W2,
                const float* __restrict__ b2, const int* __restrict__ tids,
                float* __restrict__ out)
{
    __shared__ __align__(16) char wbuf[2][NCOL * STRIDE];   // 10 KB

    const int t = threadIdx.x;
    const int lane = t & 63;
    const int w = t >> 6;
    // XCD swizzle: blocks b and b+8 (same XCD) are the two M-halves of one task-group
    const int sw = (blockIdx.x & 7) * 128 + (blockIdx.x >> 3);
    const int tg = sw >> 1;     // task-group 0..511
    const int mh = sw & 1;      // M-half: rows mh*128 .. +127

    // ---- W1 staging: thread covers (task tl, o) row srow, k-quarter sq (8 floats)
    const int srow = t >> 2;    // 0..63
    const int sq   = t & 3;     // 0..3
    const int stask = tids[tg * TPB + (srow >> 3)];
    const float* sgp = W1 + (size_t)stask * (8 * HID) + (size_t)(srow & 7) * HID + sq * 8;
    char* const swr0 = &wbuf[0][0] + srow * STRIDE + sq * 16;
    char* const swr1 = swr0 + NCOL * STRIDE;

    // ---- A fragments: wave w owns rows mh*128 + w*32 .. +31 (2 M-tiles)
    const __bf16* agp = embb + (size_t)(mh * 128 + w * 32 + (lane & 15)) * HID + (lane >> 4) * 8;
    const int boff = (lane & 15) * STRIDE + (lane >> 4) * 16;
    const char* const rb0 = &wbuf[0][0];
    const char* const rb1 = &wbuf[1][0];

    f32x4 acc[2][4];
    const f32x4 zero = {0.f, 0.f, 0.f, 0.f};
#pragma unroll
    for (int i = 0; i < 2; ++i)
#pragma unroll
        for (int j = 0; j < 4; ++j) acc[i][j] = zero;

    // ---- prologue: W(0) -> LDS0; W(1) -> slotB; A(0) -> acur
    float4 wa0 = *(const float4*)(sgp);
    float4 wa1 = *(const float4*)(sgp + 4);
    bf16x8 acur0 = *(const bf16x8*)(agp);
    bf16x8 acur1 = *(const bf16x8*)(agp + 16 * HID);
    *(bf16x8*)swr0 = cvt8(wa0, wa1);
    float4 wb0 = *(const float4*)(sgp + KC);
    float4 wb1 = *(const float4*)(sgp + KC + 4);
    __syncthreads();

    // ---- main loop: 15 double-steps cover s = 0..29 (all loads in-bounds)
    for (int i = 0; i < 15; ++i) {
        const int s = 2 * i;
        {   // even s: read buf0, write slotB->buf1, load W(s+2)->slotA, A(s+1)
            wa0 = *(const float4*)(sgp + (s + 2) * KC);
            wa1 = *(const float4*)(sgp + (s + 2) * KC + 4);
            bf16x8 an0 = *(const bf16x8*)(agp + (s + 1) * KC);
            bf16x8 an1 = *(const bf16x8*)(agp + (s + 1) * KC + 16 * HID);
#pragma unroll
            for (int nt = 0; nt < 4; ++nt) {
                bf16x8 bf = *(const bf16x8*)(rb0 + nt * (16 * STRIDE) + boff);
                acc[0][nt] = __builtin_amdgcn_mfma_f32_16x16x32_bf16(acur0, bf, acc[0][nt], 0, 0, 0);
                acc[1][nt] = __builtin_amdgcn_mfma_f32_16x16x32_bf16(acur1, bf, acc[1][nt], 0, 0, 0);
            }
            *(bf16x8*)swr1 = cvt8(wb0, wb1);
            acur0 = an0; acur1 = an1;
            __syncthreads();
        }
        {   // odd s+1: read buf1, write slotA->buf0, load W(s+3)->slotB, A(s+2)
            wb0 = *(const float4*)(sgp + (s + 3) * KC);
            wb1 = *(const float4*)(sgp + (s + 3) * KC + 4);
            bf16x8 an0 = *(const bf16x8*)(agp + (s + 2) * KC);
            bf16x8 an1 = *(const bf16x8*)(agp + (s + 2) * KC + 16 * HID);
#pragma unroll
            for (int nt = 0; nt < 4; ++nt) {
                bf16x8 bf = *(const bf16x8*)(rb1 + nt * (16 * STRIDE) + boff);
                acc[0][nt] = __builtin_amdgcn_mfma_f32_16x16x32_bf16(acur0, bf, acc[0][nt], 0, 0, 0);
                acc[1][nt] = __builtin_amdgcn_mfma_f32_16x16x32_bf16(acur1, bf, acc[1][nt], 0, 0, 0);
            }
            *(bf16x8*)swr0 = cvt8(wa0, wa1);
            acur0 = an0; acur1 = an1;
            __syncthreads();
        }
    }
    {   // s = 30: read buf0, write slotB (=W(31)) -> buf1, A(31)
        bf16x8 an0 = *(const bf16x8*)(agp + 31 * KC);
        bf16x8 an1 = *(const bf16x8*)(agp + 31 * KC + 16 * HID);
#pragma unroll
        for (int nt = 0; nt < 4; ++nt) {
            bf16x8 bf = *(const bf16x8*)(rb0 + nt * (16 * STRIDE) + boff);
            acc[0][nt] = __builtin_amdgcn_mfma_f32_16x16x32_bf16(acur0, bf, acc[0][nt], 0, 0, 0);
            acc[1][nt] = __builtin_amdgcn_mfma_f32_16x16x32_bf16(acur1, bf, acc[1][nt], 0, 0, 0);
        }
        *(bf16x8*)swr1 = cvt8(wb0, wb1);
        acur0 = an0; acur1 = an1;
        __syncthreads();
    }
    {   // s = 31: read buf1, no write, no barrier
#pragma unroll
        for (int nt = 0; nt < 4; ++nt) {
            bf16x8 bf = *(const bf16x8*)(rb1 + nt * (16 * STRIDE) + boff);
            acc[0][nt] = __builtin_amdgcn_mfma_f32_16x16x32_bf16(acur0, bf, acc[0][nt], 0, 0, 0);
            acc[1][nt] = __builtin_amdgcn_mfma_f32_16x16x32_bf16(acur1, bf, acc[1][nt], 0, 0, 0);
        }
    }

    // ---- epilogue: +b1, relu, *w2, shuffle-reduce over o (8 lanes), +b2, store
    const int col = lane & 15;
    const int rgrp = lane >> 4;
    const int o = col & 7;
#pragma unroll
    for (int nt = 0; nt < 4; ++nt) {
        const int tl = nt * 2 + (col >> 3);
        const int task = tids[tg * TPB + tl];
        const float bb1 = b1[task * 8 + o];
        const float ww2 = W2[task * 8 + o];
#pragma unroll
        for (int bt = 0; bt < 2; ++bt) {
            float v[4];
#pragma unroll
            for (int r = 0; r < 4; ++r) {
                float x = acc[bt][nt][r] + bb1;
                x = x > 0.f ? x : 0.f;
                v[r] = x * ww2;
            }
#pragma unroll
            for (int m = 1; m <= 4; m <<= 1) {
#pragma unroll
                for (int r = 0; r < 4; ++r) v[r] += __shfl_xor(v[r], m, 64);
            }
            if ((lane & 7) == 0) {
                const float bb2 = b2[task];
                const int brow = mh * 128 + w * 32 + bt * 16 + rgrp * 4;
                float4 o4 = make_float4(v[0] + bb2, v[1] + bb2, v[2] + bb2, v[3] + bb2);
                *(float4*)(out + (size_t)(tg * TPB + tl) * BATCH + brow) = o4;
            }
        }
    }
}

extern "C" void kernel_launch(void* const* d_in, const int* in_sizes, int n_in,
                              void* d_out, int out_size, void* d_ws, size_t ws_size,
                              hipStream_t stream) {
    const float* emb = (const float*)d_in[0];
    const float* W1  = (const float*)d_in[1];
    const float* b1  = (const float*)d_in[2];
    const float* W2  = (const float*)d_in[3];
    const float* b2  = (const float*)d_in[4];
    const int*   tid = (const int*)d_in[5];
    float* outp = (float*)d_out;
    __bf16* embb = (__bf16*)d_ws;   // 512 KB

    cvt_emb_kernel<<<dim3(BATCH * HID / (256 * 4)), dim3(256), 0, stream>>>(emb, embb);
    mtc_kernel<<<dim3(1024), dim3(256), 0, stream>>>(embb, W1, b1, W2, b2, tid, outp);
}